// Round 1
// baseline (1375.945 us; speedup 1.0000x reference)
//
#include <hip/hip_runtime.h>
#include <cstdint>

#define BATCH 16
#define HH 512
#define WW 512
#define T 16
#define NT 256

// ws layout (floats): wt1 @0 (864), wt2 @864 (2592), wt3 @3456 (2592), green @8192 (16*2*512*512)
#define WT1_OFF 0
#define WT2_OFF 864
#define WT3_OFF 3456
#define GREEN_OFF 8192

// ---------------- weight transpose: [co][ci][ky][kx] -> [k][ci][co(F:0-11,W:12-23)] ----------------
__global__ void wt_kernel(const float* __restrict__ fw0, const float* __restrict__ fw1,
                          const float* __restrict__ fw2, const float* __restrict__ ww0,
                          const float* __restrict__ ww1, const float* __restrict__ ww2,
                          float* __restrict__ ws) {
    const int t = blockIdx.x * 256 + threadIdx.x;
    if (t < 864) {
        const int co = t % 24, ci = (t / 24) % 4, k = t / 96;
        ws[WT1_OFF + t] = (co < 12) ? fw0[(co * 4 + ci) * 9 + k]
                                    : ww0[((co - 12) * 4 + ci) * 9 + k];
    }
    if (t < 2592) {
        const int co = t % 24, ci = (t / 24) % 12, k = t / 288;
        ws[WT2_OFF + t] = (co < 12) ? fw1[(co * 12 + ci) * 9 + k]
                                    : ww1[((co - 12) * 12 + ci) * 9 + k];
        ws[WT3_OFF + t] = (co < 12) ? fw2[(co * 12 + ci) * 9 + k]
                                    : ww2[((co - 12) * 12 + ci) * 9 + k];
    }
}

// ---------------- fused 3-conv x 2 paths + softmax + green ----------------
__global__ __launch_bounds__(NT, 2)
void green_kernel(const float* __restrict__ mosaic, const float* __restrict__ ws,
                  float* __restrict__ green) {
    __shared__ float sm[4][22][22];    // mosaic tile, origin (by*T-3, bx*T-3)
    __shared__ float sAf[12][20][20];  // f0, origin -2
    __shared__ float sAw[12][20][20];  // w0, origin -2
    __shared__ float sBf[12][18][18];  // f1, origin -1
    __shared__ float sBw[12][18][18];  // w1, origin -1

    const int tid = threadIdx.x;
    const int bx = blockIdx.x & 31;
    const int by = (blockIdx.x >> 5) & 31;
    const int b  = blockIdx.x >> 10;
    const int mx0 = bx * T - 3, my0 = by * T - 3;

    // ---- load mosaic tile (zero-padded outside image) ----
    for (int i = tid; i < 4 * 22 * 22; i += NT) {
        const int x = i % 22, y = (i / 22) % 22, c = i / 484;
        const int gx = mx0 + x, gy = my0 + y;
        float v = 0.f;
        if ((unsigned)gx < WW && (unsigned)gy < HH)
            v = mosaic[((b * 4 + c) * HH + gy) * WW + gx];
        sm[c][y][x] = v;
    }
    __syncthreads();

    const float* __restrict__ wt1 = ws + WT1_OFF;
    const float* __restrict__ wt2 = ws + WT2_OFF;
    const float* __restrict__ wt3 = ws + WT3_OFF;

    // ---- stage 1: f0/w0 at 20x20 (conv 4->12, both paths share mosaic reads) ----
    for (int idx = tid; idx < 20 * 20; idx += NT) {
        const int fx = idx % 20, fy = idx / 20;
        float aF[12], aW[12];
#pragma unroll
        for (int c = 0; c < 12; ++c) { aF[c] = 0.f; aW[c] = 0.f; }
        for (int k = 0; k < 9; ++k) {
            const int ky = k / 3, kx = k % 3;
#pragma unroll
            for (int ci = 0; ci < 4; ++ci) {
                const float v = sm[ci][fy + ky][fx + kx];
                const float* __restrict__ wp = wt1 + (k * 4 + ci) * 24;
#pragma unroll
                for (int co = 0; co < 12; ++co) {
                    aF[co] = fmaf(wp[co], v, aF[co]);
                    aW[co] = fmaf(wp[co + 12], v, aW[co]);
                }
            }
        }
        // reference zero-pads INTERMEDIATE activations at image boundary:
        const int gfy = by * T - 2 + fy, gfx = bx * T - 2 + fx;
        const bool inimg = ((unsigned)gfx < WW) && ((unsigned)gfy < HH);
#pragma unroll
        for (int co = 0; co < 12; ++co) {
            sAf[co][fy][fx] = inimg ? fmaxf(aF[co], 0.f) : 0.f;
            sAw[co][fy][fx] = inimg ? fmaxf(aW[co], 0.f) : 0.f;
        }
    }
    __syncthreads();

    // ---- stage 2: f1/w1 at 18x18 (conv 12->12) ----
    for (int idx = tid; idx < 18 * 18; idx += NT) {
        const int fx = idx % 18, fy = idx / 18;
        float aF[12], aW[12];
#pragma unroll
        for (int c = 0; c < 12; ++c) { aF[c] = 0.f; aW[c] = 0.f; }
        for (int k = 0; k < 9; ++k) {
            const int ky = k / 3, kx = k % 3;
#pragma unroll
            for (int ci = 0; ci < 12; ++ci) {
                const float vF = sAf[ci][fy + ky][fx + kx];
                const float vW = sAw[ci][fy + ky][fx + kx];
                const float* __restrict__ wp = wt2 + (k * 12 + ci) * 24;
#pragma unroll
                for (int co = 0; co < 12; ++co) {
                    aF[co] = fmaf(wp[co], vF, aF[co]);
                    aW[co] = fmaf(wp[co + 12], vW, aW[co]);
                }
            }
        }
        const int gfy = by * T - 1 + fy, gfx = bx * T - 1 + fx;
        const bool inimg = ((unsigned)gfx < WW) && ((unsigned)gfy < HH);
#pragma unroll
        for (int co = 0; co < 12; ++co) {
            sBf[co][fy][fx] = inimg ? fmaxf(aF[co], 0.f) : 0.f;
            sBw[co][fy][fx] = inimg ? fmaxf(aW[co], 0.f) : 0.f;
        }
    }
    __syncthreads();

    // ---- stage 3: conv3 (both paths) + softmax + weighted green sums, 16x16 ----
    {
        const int fx = tid % 16, fy = tid / 16;
        float aF[12], aW[12];
#pragma unroll
        for (int c = 0; c < 12; ++c) { aF[c] = 0.f; aW[c] = 0.f; }
        for (int k = 0; k < 9; ++k) {
            const int ky = k / 3, kx = k % 3;
#pragma unroll
            for (int ci = 0; ci < 12; ++ci) {
                const float vF = sBf[ci][fy + ky][fx + kx];
                const float vW = sBw[ci][fy + ky][fx + kx];
                const float* __restrict__ wp = wt3 + (k * 12 + ci) * 24;
#pragma unroll
                for (int co = 0; co < 12; ++co) {
                    aF[co] = fmaf(wp[co], vF, aF[co]);
                    aW[co] = fmaf(wp[co + 12], vW, aW[co]);
                }
            }
        }
        float m = 0.f;  // all relu'd values >= 0
#pragma unroll
        for (int c = 0; c < 12; ++c) {
            aF[c] = fmaxf(aF[c], 0.f);
            aW[c] = fmaxf(aW[c], 0.f);
            m = fmaxf(m, aW[c]);
        }
        float sum = 0.f, s0 = 0.f, s1 = 0.f;
#pragma unroll
        for (int c = 0; c < 12; ++c) {
            const float e = __expf(aW[c] - m);
            sum += e;
            if (c < 6) s0 = fmaf(aF[c], e, s0);
            else       s1 = fmaf(aF[c], e, s1);
        }
        const float inv = 1.f / sum;
        const int gy = by * T + fy, gx = bx * T + fx;
        green[((b * 2 + 0) * HH + gy) * WW + gx] = s0 * inv;
        green[((b * 2 + 1) * HH + gy) * WW + gx] = s1 * inv;
    }
}

// ---------------- chroma conv 2->6 + pixel-shuffle assembly ----------------
__global__ __launch_bounds__(256)
void assemble_kernel(const float* __restrict__ mosaic, const float* __restrict__ green,
                     const float* __restrict__ cw0, float* __restrict__ out) {
    const int t = blockIdx.x * 256 + threadIdx.x;
    const int x = t & (WW - 1);
    const int y = (t >> 9) & (HH - 1);
    const int b = t >> 18;

    const int p = y * WW + x;
    const float* __restrict__ mb = mosaic + (size_t)b * 4 * HH * WW;
    const float* __restrict__ gb = green + (size_t)b * 2 * HH * WW;

    const float m0 = mb[p];
    const float m1 = mb[HH * WW + p];
    const float m2 = mb[2 * HH * WW + p];
    const float m3 = mb[3 * HH * WW + p];
    const float g0 = gb[p];
    const float g1 = gb[HH * WW + p];

    float cd[6] = {0.f, 0.f, 0.f, 0.f, 0.f, 0.f};
#pragma unroll
    for (int ky = 0; ky < 3; ++ky) {
#pragma unroll
        for (int kx = 0; kx < 3; ++kx) {
            const int yy = y + ky - 1, xx = x + kx - 1;
            float c0 = 0.f, c1 = 0.f;
            if ((unsigned)yy < HH && (unsigned)xx < WW) {
                const int q = yy * WW + xx;
                c0 = mb[HH * WW + q]     - gb[q];            // m1 - green_rb0
                c1 = mb[2 * HH * WW + q] - gb[HH * WW + q];  // m2 - green_rb1
            }
            const int k = ky * 3 + kx;
#pragma unroll
            for (int o = 0; o < 6; ++o) {
                cd[o] = fmaf(c0, cw0[(o * 2 + 0) * 9 + k], cd[o]);
                cd[o] = fmaf(c1, cw0[(o * 2 + 1) * 9 + k], cd[o]);
            }
        }
    }
    // green_add = [m0, g1, m3, m0, g0, m3]
    const float cp0 = cd[0] + m0;
    const float cp1 = cd[1] + g1;
    const float cp2 = cd[2] + m3;
    const float cp3 = cd[3] + m0;
    const float cp4 = cd[4] + g0;
    const float cp5 = cd[5] + m3;

    const int W2 = 2 * WW;
    const size_t plane = (size_t)(2 * HH) * W2;
    size_t base = ((size_t)(b * 3) * (2 * HH) + 2 * y) * W2 + 2 * x;
    // R: tl=cp0 tr=m1 / bl=cp1 br=cp2
    *(float2*)(out + base)          = make_float2(cp0, m1);
    *(float2*)(out + base + W2)     = make_float2(cp1, cp2);
    // G: tl=m0 tr=g0 / bl=g1 br=m3
    *(float2*)(out + base + plane)          = make_float2(m0, g0);
    *(float2*)(out + base + plane + W2)     = make_float2(g1, m3);
    // B: tl=cp3 tr=cp4 / bl=m2 br=cp5
    *(float2*)(out + base + 2 * plane)      = make_float2(cp3, cp4);
    *(float2*)(out + base + 2 * plane + W2) = make_float2(m2, cp5);
}

extern "C" void kernel_launch(void* const* d_in, const int* in_sizes, int n_in,
                              void* d_out, int out_size, void* d_ws, size_t ws_size,
                              hipStream_t stream) {
    const float* mosaic = (const float*)d_in[0];
    const float* fw0 = (const float*)d_in[1];
    const float* fw1 = (const float*)d_in[2];
    const float* fw2 = (const float*)d_in[3];
    const float* ww0 = (const float*)d_in[4];
    const float* ww1 = (const float*)d_in[5];
    const float* ww2 = (const float*)d_in[6];
    const float* cw0 = (const float*)d_in[7];
    float* ws = (float*)d_ws;
    float* green = ws + GREEN_OFF;
    float* out = (float*)d_out;

    wt_kernel<<<11, 256, 0, stream>>>(fw0, fw1, fw2, ww0, ww1, ww2, ws);
    green_kernel<<<BATCH * 32 * 32, NT, 0, stream>>>(mosaic, ws, green);
    assemble_kernel<<<(BATCH * HH * WW) / 256, 256, 0, stream>>>(mosaic, green, cw0, out);
}

// Round 2
// 443.688 us; speedup vs baseline: 3.1012x; 3.1012x over previous
//
#include <hip/hip_runtime.h>
#include <cstdint>

#define HH 512
#define WW 512

typedef __attribute__((ext_vector_type(8)))  short    short8;
typedef __attribute__((ext_vector_type(16))) float    f32x16;
typedef __attribute__((ext_vector_type(2)))  unsigned u32x2;

union FragU { uint4 u; short8 s; };
union B8U   { u32x2 u2[2]; short8 s; };

__device__ __forceinline__ unsigned short f2bf(float f) {
  union { float f; unsigned u; } v; v.f = f;
  unsigned r = v.u + 0x7fffu + ((v.u >> 16) & 1u);
  return (unsigned short)(r >> 16);
}
__device__ __forceinline__ float bf2f(unsigned short b) {
  union { unsigned u; float f; } v; v.u = ((unsigned)b) << 16;
  return v.f;
}
__device__ __forceinline__ unsigned pk2(float a, float b) {
  return (unsigned)f2bf(a) | ((unsigned)f2bf(b) << 16);
}

// ---- LDS layout (bytes). mosaic aliases L3W (mosaic dead after last L1 pass,
// L3W written in the final pass, barriers in between). ----
#define L1OFF  0
#define L1RST  1632      // 68 px * 24B
#define L2OFF  19584
#define L2RST  1584      // 66 px * 24B
#define L3FOFF 35424
#define L3RST  1536      // 64 px * 24B
#define L3WOFF 47712
#define MOSOFF 47712
#define MOSRST 560       // 70 px * 8B
#define SMEMB  60000

// act slot = 24B = 12 bf16 ci. kappa = tap*12+ci, tap = ky*3+kx.
// kappa-quad q: row = ly + q/9 (origin shifts cancel), col = colpx + (q/3)%3, byte = (q%3)*8
template<int RST>
__device__ __forceinline__ const char* kqaddr(const char* inb, int ly, int colpx, int q) {
  return inb + (ly + q / 9) * RST + (colpx + (q / 3) % 3) * 24 + (q % 3) * 8;
}

// C/D layout (verified m74/m101): col=lane&31, row=(reg&3)+8*(reg>>2)+4*h.
// M=12 rows used: h==0 lanes hold ci0-3 (regs0-3) and ci8-11 (regs4-7);
// h==1 lanes hold ci4-7 (regs0-3). Write bf16 quads into the 24B px slot.
__device__ __forceinline__ void store_acts(char* dst, const f32x16 c, int h, bool inim) {
  if (h == 0) {
    float r0 = inim ? fmaxf(c[0], 0.f) : 0.f;
    float r1 = inim ? fmaxf(c[1], 0.f) : 0.f;
    float r2 = inim ? fmaxf(c[2], 0.f) : 0.f;
    float r3 = inim ? fmaxf(c[3], 0.f) : 0.f;
    float r4 = inim ? fmaxf(c[4], 0.f) : 0.f;
    float r5 = inim ? fmaxf(c[5], 0.f) : 0.f;
    float r6 = inim ? fmaxf(c[6], 0.f) : 0.f;
    float r7 = inim ? fmaxf(c[7], 0.f) : 0.f;
    u32x2 w0 = { pk2(r0, r1), pk2(r2, r3) };
    u32x2 w1 = { pk2(r4, r5), pk2(r6, r7) };
    *(u32x2*)(dst)      = w0;   // ci 0-3
    *(u32x2*)(dst + 16) = w1;   // ci 8-11
  } else {
    float r0 = inim ? fmaxf(c[0], 0.f) : 0.f;
    float r1 = inim ? fmaxf(c[1], 0.f) : 0.f;
    float r2 = inim ? fmaxf(c[2], 0.f) : 0.f;
    float r3 = inim ? fmaxf(c[3], 0.f) : 0.f;
    u32x2 w0 = { pk2(r0, r1), pk2(r2, r3) };
    *(u32x2*)(dst + 8) = w0;    // ci 4-7
  }
}

// ---------------- weight fragment packer ----------------
// 34 frags x 64 lanes x 16B. Frag f: 0-5 L1 (path*3+ky, K=kx*4+ci pad16),
// 6-19 L2 (path*7+j, kappa=16j+k), 20-33 L3. k(e,h) = (e/4)*8 + h*4 + e%4.
__global__ void wt_kernel(const float* __restrict__ fw0, const float* __restrict__ fw1,
                          const float* __restrict__ fw2, const float* __restrict__ ww0,
                          const float* __restrict__ ww1, const float* __restrict__ ww2,
                          uint4* __restrict__ wsf) {
  int t = blockIdx.x * 256 + threadIdx.x;
  if (t >= 34 * 64) return;
  int f = t >> 6, lane = t & 63;
  int h = (lane >> 5) & 1, m = lane & 31;
  unsigned short v[8];
#pragma unroll
  for (int e = 0; e < 8; ++e) {
    int k = (e / 4) * 8 + h * 4 + (e % 4);
    float w = 0.f;
    if (m < 12) {
      if (f < 6) {
        int path = f / 3, ky = f % 3;
        if (k < 12) {
          int kx = k >> 2, ci = k & 3;
          const float* src = path ? ww0 : fw0;
          w = src[(m * 4 + ci) * 9 + ky * 3 + kx];
        }
      } else {
        int fi = f - 6;
        int layer = fi / 14, rem = fi % 14, path = rem / 7, j = rem % 7;
        int kap = 16 * j + k;
        if (kap < 108) {
          int tap = kap / 12, ci = kap % 12, ky = tap / 3, kx = tap % 3;
          const float* src = layer ? (path ? ww2 : fw2) : (path ? ww1 : fw1);
          w = src[(m * 12 + ci) * 9 + ky * 3 + kx];
        }
      }
    }
    v[e] = f2bf(w);
  }
  uint4 o;
  o.x = (unsigned)v[0] | ((unsigned)v[1] << 16);
  o.y = (unsigned)v[2] | ((unsigned)v[3] << 16);
  o.z = (unsigned)v[4] | ((unsigned)v[5] << 16);
  o.w = (unsigned)v[6] | ((unsigned)v[7] << 16);
  wsf[t] = o;
}

// ---------------- fused 3-layer x 2-path conv via MFMA + softmax green ----------------
__global__ __launch_bounds__(256, 2)
void green_kernel(const float* __restrict__ mosaic, const uint4* __restrict__ wsf,
                  unsigned short* __restrict__ green) {
  __shared__ __align__(16) char s[SMEMB];
  const int tid = threadIdx.x;
  const int lane = tid & 63, wave = tid >> 6;
  const int h = (lane >> 5) & 1, ln = lane & 31;
  const int bid = blockIdx.x;
  const int bx = bid & 7, by = (bid >> 3) & 63, b = bid >> 9;
  const int X0 = bx * 64, Y0 = by * 8;

  // ---- stage 0: mosaic tile 14x70, 4ch bf16-packed (8B/px), zero outside image ----
  {
    const float* mb = mosaic + (size_t)b * 4 * HH * WW;
    for (int p = tid; p < 980; p += 256) {
      int row = p / 70, col = p - row * 70;
      int gy = Y0 + row - 3, gx = X0 + col - 3;
      float c0 = 0.f, c1 = 0.f, c2 = 0.f, c3 = 0.f;
      if ((unsigned)gy < HH && (unsigned)gx < WW) {
        const float* mp = mb + (size_t)gy * WW + gx;
        c0 = mp[0]; c1 = mp[HH * WW]; c2 = mp[2 * HH * WW]; c3 = mp[3 * HH * WW];
      }
      u32x2 w = { pk2(c0, c1), pk2(c2, c3) };
      *(u32x2*)(s + MOSOFF + row * MOSRST + col * 8) = w;
    }
  }
  __syncthreads();

  for (int path = 0; path < 2; ++path) {
    // ---- L1: 4->12, out region y rel -2..9 (ly 0..11), x rel -2..65 (col 0..67) ----
    {
      FragU a0, a1, a2;
      const uint4* ap = wsf + (path * 3) * 64 + lane;
      a0.u = ap[0]; a1.u = ap[64]; a2.u = ap[128];
      for (int g = wave; g < 36; g += 4) {
        int ly = g / 3, xg = g - ly * 3;
        int cb = (xg == 0) ? 0 : (xg == 1 ? 32 : 36);   // overlapping groups, all in-buffer
        int colpx = cb + ln;                            // L1 col = x+2, 0..67
        f32x16 c = {};
#pragma unroll
        for (int ky = 0; ky < 3; ++ky) {
          const char* r = s + MOSOFF + (ly + ky) * MOSRST + colpx * 8;
          B8U bu;
          bu.u2[0] = *(const u32x2*)(r + h * 8);   // kx = h   (k quads 0/1)
          bu.u2[1] = *(const u32x2*)(r + 16);      // kx = 2   (k quad 2; h=1 -> pad, A=0)
          const short8 af = (ky == 0) ? a0.s : (ky == 1 ? a1.s : a2.s);
          c = __builtin_amdgcn_mfma_f32_32x32x16_bf16(af, bu.s, c, 0, 0, 0);
        }
        int gy = Y0 + ly - 2, gx = X0 + colpx - 2;
        bool inim = ((unsigned)gy < HH) && ((unsigned)gx < WW);
        store_acts(s + L1OFF + ly * L1RST + colpx * 24, c, h, inim);
      }
    }
    __syncthreads();

    // ---- L2: 12->12, out y rel -1..8 (ly 0..9), x rel -1..64 (col 0..65) ----
    {
      FragU a[7];
      const uint4* ap = wsf + (6 + path * 7) * 64 + lane;
#pragma unroll
      for (int j = 0; j < 7; ++j) a[j].u = ap[j * 64];
      const char* inb = s + L1OFF;
      for (int g = wave; g < 30; g += 4) {
        int ly = g / 3, xg = g - ly * 3;
        int cb = (xg == 0) ? 0 : (xg == 1 ? 32 : 34);
        int colpx = cb + ln;                            // L2 col = x+1, 0..65
        f32x16 c = {};
#pragma unroll
        for (int j = 0; j < 7; ++j) {
          const char* plo = h ? kqaddr<L1RST>(inb, ly, colpx, 4 * j + 1)
                              : kqaddr<L1RST>(inb, ly, colpx, 4 * j);
          const char* phi = h ? kqaddr<L1RST>(inb, ly, colpx, (4 * j + 3 > 26) ? 26 : 4 * j + 3)
                              : kqaddr<L1RST>(inb, ly, colpx, 4 * j + 2);
          B8U bu; bu.u2[0] = *(const u32x2*)plo; bu.u2[1] = *(const u32x2*)phi;
          c = __builtin_amdgcn_mfma_f32_32x32x16_bf16(a[j].s, bu.s, c, 0, 0, 0);
        }
        int gy = Y0 + ly - 1, gx = X0 + colpx - 1;
        bool inim = ((unsigned)gy < HH) && ((unsigned)gx < WW);
        store_acts(s + L2OFF + ly * L2RST + colpx * 24, c, h, inim);
      }
    }
    __syncthreads();

    // ---- L3: 12->12, out y rel 0..7, x rel 0..63 (exact) ----
    {
      FragU a[7];
      const uint4* ap = wsf + (20 + path * 7) * 64 + lane;
#pragma unroll
      for (int j = 0; j < 7; ++j) a[j].u = ap[j * 64];
      const char* inb = s + L2OFF;
      char* outb = s + (path ? L3WOFF : L3FOFF);
      for (int g = wave; g < 16; g += 4) {
        int ly = g >> 1, xg = g & 1;
        int colpx = xg * 32 + ln;                       // = x, 0..63
        f32x16 c = {};
#pragma unroll
        for (int j = 0; j < 7; ++j) {
          const char* plo = h ? kqaddr<L2RST>(inb, ly, colpx, 4 * j + 1)
                              : kqaddr<L2RST>(inb, ly, colpx, 4 * j);
          const char* phi = h ? kqaddr<L2RST>(inb, ly, colpx, (4 * j + 3 > 26) ? 26 : 4 * j + 3)
                              : kqaddr<L2RST>(inb, ly, colpx, 4 * j + 2);
          B8U bu; bu.u2[0] = *(const u32x2*)plo; bu.u2[1] = *(const u32x2*)phi;
          c = __builtin_amdgcn_mfma_f32_32x32x16_bf16(a[j].s, bu.s, c, 0, 0, 0);
        }
        store_acts(outb + ly * L3RST + colpx * 24, c, h, true);
      }
    }
    __syncthreads();
  }

  // ---- softmax + weighted green sums, 64x8 px, 2 px/thread ----
  for (int i = tid; i < 512; i += 256) {
    int y = i >> 6, x = i & 63;
    const char* fp = s + L3FOFF + y * L3RST + x * 24;
    const char* wp = s + L3WOFF + y * L3RST + x * 24;
    float F[12], Wv[12];
#pragma unroll
    for (int qd = 0; qd < 3; ++qd) {
      u32x2 fu = *(const u32x2*)(fp + qd * 8);
      u32x2 wu = *(const u32x2*)(wp + qd * 8);
#pragma unroll
      for (int e = 0; e < 2; ++e) {
        F[qd * 4 + e * 2]      = bf2f((unsigned short)(fu[e] & 0xffffu));
        F[qd * 4 + e * 2 + 1]  = bf2f((unsigned short)(fu[e] >> 16));
        Wv[qd * 4 + e * 2]     = bf2f((unsigned short)(wu[e] & 0xffffu));
        Wv[qd * 4 + e * 2 + 1] = bf2f((unsigned short)(wu[e] >> 16));
      }
    }
    float m = 0.f;
#pragma unroll
    for (int c2 = 0; c2 < 12; ++c2) m = fmaxf(m, Wv[c2]);
    float sum = 0.f, s0 = 0.f, s1 = 0.f;
#pragma unroll
    for (int c2 = 0; c2 < 12; ++c2) {
      float e = __expf(Wv[c2] - m);
      sum += e;
      if (c2 < 6) s0 = fmaf(F[c2], e, s0);
      else        s1 = fmaf(F[c2], e, s1);
    }
    float inv = 1.f / sum;
    int gy = Y0 + y, gx = X0 + x;
    green[((b * 2 + 0) * HH + gy) * WW + gx] = f2bf(s0 * inv);
    green[((b * 2 + 1) * HH + gy) * WW + gx] = f2bf(s1 * inv);
  }
}

// ---------------- chroma conv 2->6 + pixel-shuffle assembly (green now bf16) ----------------
__global__ __launch_bounds__(256)
void assemble_kernel(const float* __restrict__ mosaic, const unsigned short* __restrict__ green,
                     const float* __restrict__ cw0, float* __restrict__ out) {
  const int t = blockIdx.x * 256 + threadIdx.x;
  const int x = t & (WW - 1);
  const int y = (t >> 9) & (HH - 1);
  const int b = t >> 18;

  const int p = y * WW + x;
  const float* __restrict__ mb = mosaic + (size_t)b * 4 * HH * WW;
  const unsigned short* __restrict__ gb = green + (size_t)b * 2 * HH * WW;

  const float m0 = mb[p];
  const float m1 = mb[HH * WW + p];
  const float m2 = mb[2 * HH * WW + p];
  const float m3 = mb[3 * HH * WW + p];
  const float g0 = bf2f(gb[p]);
  const float g1 = bf2f(gb[HH * WW + p]);

  float cd[6] = {0.f, 0.f, 0.f, 0.f, 0.f, 0.f};
#pragma unroll
  for (int ky = 0; ky < 3; ++ky) {
#pragma unroll
    for (int kx = 0; kx < 3; ++kx) {
      const int yy = y + ky - 1, xx = x + kx - 1;
      float c0 = 0.f, c1 = 0.f;
      if ((unsigned)yy < HH && (unsigned)xx < WW) {
        const int q = yy * WW + xx;
        c0 = mb[HH * WW + q]     - bf2f(gb[q]);
        c1 = mb[2 * HH * WW + q] - bf2f(gb[HH * WW + q]);
      }
      const int k = ky * 3 + kx;
#pragma unroll
      for (int o = 0; o < 6; ++o) {
        cd[o] = fmaf(c0, cw0[(o * 2 + 0) * 9 + k], cd[o]);
        cd[o] = fmaf(c1, cw0[(o * 2 + 1) * 9 + k], cd[o]);
      }
    }
  }
  const float cp0 = cd[0] + m0;
  const float cp1 = cd[1] + g1;
  const float cp2 = cd[2] + m3;
  const float cp3 = cd[3] + m0;
  const float cp4 = cd[4] + g0;
  const float cp5 = cd[5] + m3;

  const int W2 = 2 * WW;
  const size_t plane = (size_t)(2 * HH) * W2;
  size_t base = ((size_t)(b * 3) * (2 * HH) + 2 * y) * W2 + 2 * x;
  *(float2*)(out + base)              = make_float2(cp0, m1);
  *(float2*)(out + base + W2)         = make_float2(cp1, cp2);
  *(float2*)(out + base + plane)      = make_float2(m0, g0);
  *(float2*)(out + base + plane + W2) = make_float2(g1, m3);
  *(float2*)(out + base + 2 * plane)      = make_float2(cp3, cp4);
  *(float2*)(out + base + 2 * plane + W2) = make_float2(m2, cp5);
}

extern "C" void kernel_launch(void* const* d_in, const int* in_sizes, int n_in,
                              void* d_out, int out_size, void* d_ws, size_t ws_size,
                              hipStream_t stream) {
  const float* mosaic = (const float*)d_in[0];
  const float* fw0 = (const float*)d_in[1];
  const float* fw1 = (const float*)d_in[2];
  const float* fw2 = (const float*)d_in[3];
  const float* ww0 = (const float*)d_in[4];
  const float* ww1 = (const float*)d_in[5];
  const float* ww2 = (const float*)d_in[6];
  const float* cw0 = (const float*)d_in[7];

  uint4* wsf = (uint4*)((char*)d_ws + 32768);
  unsigned short* green = (unsigned short*)((char*)d_ws + 67584);
  float* out = (float*)d_out;

  wt_kernel<<<9, 256, 0, stream>>>(fw0, fw1, fw2, ww0, ww1, ww2, wsf);
  green_kernel<<<16 * 8 * 64, 256, 0, stream>>>(mosaic, wsf, green);
  assemble_kernel<<<(16 * HH * WW) / 256, 256, 0, stream>>>(mosaic, green, cw0, out);
}

// Round 4
// 291.901 us; speedup vs baseline: 4.7137x; 1.5200x over previous
//
#include <hip/hip_runtime.h>
#include <cstdint>

#define HH 512
#define WW 512

typedef __attribute__((ext_vector_type(8)))  short    short8;
typedef __attribute__((ext_vector_type(16))) float    f32x16;
typedef __attribute__((ext_vector_type(2)))  unsigned u32x2;

union FragU { uint4 u; short8 s; };
union B8U   { u32x2 u2[2]; short8 s; };

// ---- LDS layout (bytes) ----
#define L1F_O  0        // 12 rows x 68 px x 24B
#define L1W_O  19584
#define L1RST  1632
#define MOS_O  39168    // 14 rows x 70 px x 8B (dead after L1 pass)
#define MOSR   560
#define L2F_O  39168    // aliases mosaic; 10 x 66 x 24B
#define L2W_O  55008
#define L2RST  1584
#define L3F_O  0        // aliases dead L1; 8 x 64 x 24B
#define L3W_O  12288
#define L3RST  1536
#define SMEMB  70912

__device__ __forceinline__ unsigned cvtpk(float a, float b) {
  unsigned r;
  asm("v_cvt_pk_bf16_f32 %0, %1, %2" : "=v"(r) : "v"(a), "v"(b));
  return r;
}
__device__ __forceinline__ unsigned rp(float a, float b, bool im) {
  unsigned r = cvtpk(fmaxf(a, 0.f), fmaxf(b, 0.f));
  return im ? r : 0u;
}
__device__ __forceinline__ unsigned short f2bf(float f) {
  union { float f; unsigned u; } v; v.f = f;
  unsigned r = v.u + 0x7fffu + ((v.u >> 16) & 1u);
  return (unsigned short)(r >> 16);
}
__device__ __forceinline__ float bf2f(unsigned short b) {
  union { unsigned u; float f; } v; v.u = ((unsigned)b) << 16;
  return v.f;
}

// ---------------- weight fragment packer ----------------
// 31 frags x 64 lanes x 16B.
// f 0-2: L1 merged (ky=f), rows: 0-11 = F co (fw0), 12-23 = W co (ww0);
//        slot sq = 2h + e/4 -> kx = sq (sq==3 zero).
// f 3-9: L2 F j / 10-16: L2 W j / 17-23: L3 F j / 24-30: L3 W j.
// Quad assignment (27 quads, grid (row=q/9, u=q%9), off(q)=(q/9)*RST+8*(q%9)):
//   t=e/4==0 (B u2[0]): vertical domino  q = 9*h + j          (h-delta RST)
//   t==1     (B u2[1]): horizontal domino q = H0[j] + h        (h-delta 8)
//   H0 = {7,16,18,20,22,24,25}; slot (j=6,t=1,h=0) duplicates quad 25 -> zero weights.
__global__ void wt_kernel(const float* __restrict__ fw0, const float* __restrict__ fw1,
                          const float* __restrict__ fw2, const float* __restrict__ ww0,
                          const float* __restrict__ ww1, const float* __restrict__ ww2,
                          uint4* __restrict__ wsf) {
  int t = blockIdx.x * 256 + threadIdx.x;
  if (t >= 31 * 64) return;
  int f = t >> 6, lane = t & 63;
  int h = (lane >> 5) & 1, m = lane & 31;
  unsigned short v[8];
#pragma unroll
  for (int e = 0; e < 8; ++e) {
    int half = e >> 2;
    int c4 = e & 3;
    float w = 0.f;
    if (f < 3) {
      int sq = 2 * h + half;
      if (sq < 3 && m < 24) {
        int kx = sq;
        w = (m < 12) ? fw0[(m * 4 + c4) * 9 + f * 3 + kx]
                     : ww0[((m - 12) * 4 + c4) * 9 + f * 3 + kx];
      }
    } else {
      int fi = f - 3, layer = fi / 14, path = (fi % 14) / 7, j = fi % 7;
      int q; bool real = (m < 12);
      if (half == 0) {
        q = 9 * h + j;
      } else {
        const int H0[7] = {7, 16, 18, 20, 22, 24, 25};
        q = H0[j] + h;
        if (j == 6 && h == 0) real = false;   // duplicate coverage of quad 25
      }
      if (real) {
        int tap = q / 3, ci = (q % 3) * 4 + c4;
        const float* src = layer ? (path ? ww2 : fw2) : (path ? ww1 : fw1);
        w = src[(m * 12 + ci) * 9 + tap];
      }
    }
    v[e] = f2bf(w);
  }
  uint4 o;
  o.x = (unsigned)v[0] | ((unsigned)v[1] << 16);
  o.y = (unsigned)v[2] | ((unsigned)v[3] << 16);
  o.z = (unsigned)v[4] | ((unsigned)v[5] << 16);
  o.w = (unsigned)v[6] | ((unsigned)v[7] << 16);
  wsf[t] = o;
}

// dual 12->12 conv group: 7 MFMAs each on F and W chains.
// P0 = slotbase + h*RSTIN (vertical-domino reads), P1 = slotbase + h*8 (horizontal).
// All offsets compile-time immediates.
template<int RSTIN, int WIN>
__device__ __forceinline__ void conv12(const FragU* aF, const FragU* aW,
                                       const char* P0, const char* P1, int imm,
                                       f32x16& cF, f32x16& cW) {
  const int HI[7] = {56, RSTIN + 56, 2 * RSTIN, 2 * RSTIN + 16,
                     2 * RSTIN + 32, 2 * RSTIN + 48, 2 * RSTIN + 56};
#pragma unroll
  for (int j = 0; j < 7; ++j) {
    B8U bF, bW;
    bF.u2[0] = *(const u32x2*)(P0 + imm + 8 * j);
    bF.u2[1] = *(const u32x2*)(P1 + imm + HI[j]);
    bW.u2[0] = *(const u32x2*)(P0 + imm + 8 * j + WIN);
    bW.u2[1] = *(const u32x2*)(P1 + imm + HI[j] + WIN);
    cF = __builtin_amdgcn_mfma_f32_32x32x16_bf16(aF[j].s, bF.s, cF, 0, 0, 0);
    cW = __builtin_amdgcn_mfma_f32_32x32x16_bf16(aW[j].s, bW.s, cW, 0, 0, 0);
  }
}

// store M=12 C/D (rows: h0 regs0-3->ci0-3, regs4-7->ci8-11; h1 regs0-3->ci4-7)
template<int WOUT>
__device__ __forceinline__ void store12(char* pO, int imm, const f32x16& cF,
                                        const f32x16& cW, bool im, int h) {
  u32x2 o;
  o.x = rp(cF[0], cF[1], im); o.y = rp(cF[2], cF[3], im);
  *(u32x2*)(pO + imm) = o;
  o.x = rp(cW[0], cW[1], im); o.y = rp(cW[2], cW[3], im);
  *(u32x2*)(pO + imm + WOUT) = o;
  if (h == 0) {
    o.x = rp(cF[4], cF[5], im); o.y = rp(cF[6], cF[7], im);
    *(u32x2*)(pO + imm + 16) = o;
    o.x = rp(cW[4], cW[5], im); o.y = rp(cW[6], cW[7], im);
    *(u32x2*)(pO + imm + WOUT + 16) = o;
  }
}

// ---------------- fused 3-layer x 2-path conv via MFMA + softmax green ----------------
__global__ __launch_bounds__(256, 2)
void green_kernel(const float* __restrict__ mosaic, const uint4* __restrict__ wsf,
                  unsigned short* __restrict__ green) {
  __shared__ __align__(16) char s[SMEMB];
  const int tid = threadIdx.x;
  const int lane = tid & 63;
  const int wv = __builtin_amdgcn_readfirstlane(tid >> 6);
  const int h = (lane >> 5) & 1, ln = lane & 31;
  const int ln8 = ln * 8, ln24 = ln * 24;
  const int bid = blockIdx.x;
  const int bx = bid & 7, by = (bid >> 3) & 63, b = bid >> 9;
  const int X0 = bx * 64, Y0 = by * 8;

  // ---- stage 0: mosaic tile 14x70, 4ch bf16-packed (8B/px), zero outside image ----
  {
    const float* mb = mosaic + (size_t)b * 4 * HH * WW;
    for (int p = tid; p < 980; p += 256) {
      int row = p / 70, col = p - row * 70;
      int gy = Y0 + row - 3, gx = X0 + col - 3;
      float c0 = 0.f, c1 = 0.f, c2 = 0.f, c3 = 0.f;
      if ((unsigned)gy < HH && (unsigned)gx < WW) {
        const float* mp = mb + (size_t)gy * WW + gx;
        c0 = mp[0]; c1 = mp[HH * WW]; c2 = mp[2 * HH * WW]; c3 = mp[3 * HH * WW];
      }
      u32x2 w = { cvtpk(c0, c1), cvtpk(c2, c3) };
      *(u32x2*)(s + MOS_O + row * MOSR + col * 8) = w;
    }
  }
  __syncthreads();

  // ---- L1: 4->12 both paths in one MFMA (M: F 0-11, W 12-23), out 12x68 ----
  {
    FragU a3[3];
#pragma unroll
    for (int q = 0; q < 3; ++q) a3[q].u = wsf[q * 64 + lane];
    const char* pLo = s + MOS_O + 3 * wv * MOSR + ln8 + 16 * h;  // sem kx = 2h
    const char* pHi = s + MOS_O + 3 * wv * MOSR + ln8 + 8;       // sem kx=1 (h0); pad (h1)
    char* pA = s + 3 * wv * L1RST + ln24 + (h ? L1F_O + 8  : L1F_O + 0);
    char* pB = s + 3 * wv * L1RST + ln24 + (h ? L1W_O + 0  : L1F_O + 16);
    char* pC = s + 3 * wv * L1RST + ln24 + (h ? L1W_O + 16 : L1W_O + 8);
    bool ck[3];
    ck[0] = (unsigned)(X0 + 0  + ln - 2) < WW;
    ck[1] = (unsigned)(X0 + 32 + ln - 2) < WW;
    ck[2] = (unsigned)(X0 + 36 + ln - 2) < WW;
#pragma unroll
    for (int r = 0; r < 3; ++r) {
      const int ly = 3 * wv + r;
      const bool rowok = (unsigned)(Y0 + ly - 2) < HH;
#pragma unroll
      for (int g = 0; g < 3; ++g) {
        const int cb = (g == 0) ? 0 : (g == 1 ? 32 : 36);
        f32x16 c = {};
#pragma unroll
        for (int ky = 0; ky < 3; ++ky) {
          B8U bu;
          bu.u2[0] = *(const u32x2*)(pLo + (r + ky) * MOSR + cb * 8);
          bu.u2[1] = *(const u32x2*)(pHi + (r + ky) * MOSR + cb * 8);
          c = __builtin_amdgcn_mfma_f32_32x32x16_bf16(a3[ky].s, bu.s, c, 0, 0, 0);
        }
        const bool im = rowok && ck[g];
        u32x2 o;
        o.x = rp(c[0], c[1], im);   o.y = rp(c[2], c[3], im);
        *(u32x2*)(pA + r * L1RST + cb * 24) = o;   // h0: F ci0-3 | h1: F ci4-7
        o.x = rp(c[4], c[5], im);   o.y = rp(c[6], c[7], im);
        *(u32x2*)(pB + r * L1RST + cb * 24) = o;   // h0: F ci8-11 | h1: W ci0-3
        o.x = rp(c[8], c[9], im);   o.y = rp(c[10], c[11], im);
        *(u32x2*)(pC + r * L1RST + cb * 24) = o;   // h0: W ci4-7 | h1: W ci8-11
      }
    }
  }
  __syncthreads();

  // ---- L2: 12->12 both chains, out 10x66 ----
  {
    FragU aF[7], aW[7];
#pragma unroll
    for (int j = 0; j < 7; ++j) {
      aF[j].u = wsf[(3 + j) * 64 + lane];
      aW[j].u = wsf[(10 + j) * 64 + lane];
    }
    const char* P0 = s + L1F_O + (wv + h) * L1RST + ln24;
    const char* P1 = s + L1F_O + wv * L1RST + ln24 + 8 * h;
    char* bO0 = s + L2F_O + wv * L2RST + ln24 + (h ? 8 : 0);
    bool ck[3];
    ck[0] = (unsigned)(X0 + 0  + ln - 1) < WW;
    ck[1] = (unsigned)(X0 + 32 + ln - 1) < WW;
    ck[2] = (unsigned)(X0 + 34 + ln - 1) < WW;
#pragma unroll
    for (int i = 0; i < 3; ++i) {
      const int ly = wv + 4 * i;
      if (ly < 10) {
        const bool rowok = (unsigned)(Y0 + ly - 1) < HH;
#pragma unroll
        for (int g = 0; g < 3; ++g) {
          const int cb = (g == 0) ? 0 : (g == 1 ? 32 : 34);
          f32x16 cF = {}, cW = {};
          conv12<L1RST, 19584>(aF, aW, P0, P1, i * 4 * L1RST + cb * 24, cF, cW);
          store12<15840>(bO0, i * 4 * L2RST + cb * 24, cF, cW, rowok && ck[g], h);
        }
      }
    }
  }
  __syncthreads();

  // ---- L3: 12->12 both chains, out 8x64 exact ----
  {
    FragU aF[7], aW[7];
#pragma unroll
    for (int j = 0; j < 7; ++j) {
      aF[j].u = wsf[(17 + j) * 64 + lane];
      aW[j].u = wsf[(24 + j) * 64 + lane];
    }
    const char* P0 = s + L2F_O + (2 * wv + h) * L2RST + ln24;
    const char* P1 = s + L2F_O + 2 * wv * L2RST + ln24 + 8 * h;
    char* bO0 = s + L3F_O + 2 * wv * L3RST + ln24 + (h ? 8 : 0);
#pragma unroll
    for (int r = 0; r < 2; ++r) {
#pragma unroll
      for (int g = 0; g < 2; ++g) {
        const int cb = g * 32;
        f32x16 cF = {}, cW = {};
        conv12<L2RST, 15840>(aF, aW, P0, P1, r * L2RST + cb * 24, cF, cW);
        store12<12288>(bO0, r * L3RST + cb * 24, cF, cW, true, h);
      }
    }
  }
  __syncthreads();

  // ---- softmax + weighted green sums, 64x8 px, 2 px/thread ----
  for (int i = tid; i < 512; i += 256) {
    int y = i >> 6, x = i & 63;
    const char* fp = s + L3F_O + y * L3RST + x * 24;
    const char* wp = s + L3W_O + y * L3RST + x * 24;
    float F[12], Wv[12];
#pragma unroll
    for (int qd = 0; qd < 3; ++qd) {
      u32x2 fu = *(const u32x2*)(fp + qd * 8);
      u32x2 wu = *(const u32x2*)(wp + qd * 8);
#pragma unroll
      for (int e = 0; e < 2; ++e) {
        F[qd * 4 + e * 2]      = bf2f((unsigned short)(fu[e] & 0xffffu));
        F[qd * 4 + e * 2 + 1]  = bf2f((unsigned short)(fu[e] >> 16));
        Wv[qd * 4 + e * 2]     = bf2f((unsigned short)(wu[e] & 0xffffu));
        Wv[qd * 4 + e * 2 + 1] = bf2f((unsigned short)(wu[e] >> 16));
      }
    }
    float m = 0.f;
#pragma unroll
    for (int c2 = 0; c2 < 12; ++c2) m = fmaxf(m, Wv[c2]);
    float sum = 0.f, s0 = 0.f, s1 = 0.f;
#pragma unroll
    for (int c2 = 0; c2 < 12; ++c2) {
      float e = __expf(Wv[c2] - m);
      sum += e;
      if (c2 < 6) s0 = fmaf(F[c2], e, s0);
      else        s1 = fmaf(F[c2], e, s1);
    }
    float inv = 1.f / sum;
    unsigned pg = cvtpk(s0 * inv, s1 * inv);
    int gy = Y0 + y, gx = X0 + x;
    green[((b * 2 + 0) * HH + gy) * WW + gx] = (unsigned short)pg;
    green[((b * 2 + 1) * HH + gy) * WW + gx] = (unsigned short)(pg >> 16);
  }
}

// ---------------- chroma conv 2->6 + pixel-shuffle assembly ----------------
__global__ __launch_bounds__(256)
void assemble_kernel(const float* __restrict__ mosaic, const unsigned short* __restrict__ green,
                     const float* __restrict__ cw0, float* __restrict__ out) {
  const int t = blockIdx.x * 256 + threadIdx.x;
  const int x = t & (WW - 1);
  const int y = (t >> 9) & (HH - 1);
  const int b = t >> 18;

  const int p = y * WW + x;
  const float* __restrict__ mb = mosaic + (size_t)b * 4 * HH * WW;
  const unsigned short* __restrict__ gb = green + (size_t)b * 2 * HH * WW;

  const float m0 = mb[p];
  const float m1 = mb[HH * WW + p];
  const float m2 = mb[2 * HH * WW + p];
  const float m3 = mb[3 * HH * WW + p];
  const float g0 = bf2f(gb[p]);
  const float g1 = bf2f(gb[HH * WW + p]);

  float cd[6] = {0.f, 0.f, 0.f, 0.f, 0.f, 0.f};
#pragma unroll
  for (int ky = 0; ky < 3; ++ky) {
#pragma unroll
    for (int kx = 0; kx < 3; ++kx) {
      const int yy = y + ky - 1, xx = x + kx - 1;
      float c0 = 0.f, c1 = 0.f;
      if ((unsigned)yy < HH && (unsigned)xx < WW) {
        const int q = yy * WW + xx;
        c0 = mb[HH * WW + q]     - bf2f(gb[q]);
        c1 = mb[2 * HH * WW + q] - bf2f(gb[HH * WW + q]);
      }
      const int k = ky * 3 + kx;
#pragma unroll
      for (int o = 0; o < 6; ++o) {
        cd[o] = fmaf(c0, cw0[(o * 2 + 0) * 9 + k], cd[o]);
        cd[o] = fmaf(c1, cw0[(o * 2 + 1) * 9 + k], cd[o]);
      }
    }
  }
  const float cp0 = cd[0] + m0;
  const float cp1 = cd[1] + g1;
  const float cp2 = cd[2] + m3;
  const float cp3 = cd[3] + m0;
  const float cp4 = cd[4] + g0;
  const float cp5 = cd[5] + m3;

  const int W2 = 2 * WW;
  const size_t plane = (size_t)(2 * HH) * W2;
  size_t base = ((size_t)(b * 3) * (2 * HH) + 2 * y) * W2 + 2 * x;
  *(float2*)(out + base)              = make_float2(cp0, m1);
  *(float2*)(out + base + W2)         = make_float2(cp1, cp2);
  *(float2*)(out + base + plane)      = make_float2(m0, g0);
  *(float2*)(out + base + plane + W2) = make_float2(g1, m3);
  *(float2*)(out + base + 2 * plane)      = make_float2(cp3, cp4);
  *(float2*)(out + base + 2 * plane + W2) = make_float2(m2, cp5);
}

extern "C" void kernel_launch(void* const* d_in, const int* in_sizes, int n_in,
                              void* d_out, int out_size, void* d_ws, size_t ws_size,
                              hipStream_t stream) {
  const float* mosaic = (const float*)d_in[0];
  const float* fw0 = (const float*)d_in[1];
  const float* fw1 = (const float*)d_in[2];
  const float* fw2 = (const float*)d_in[3];
  const float* ww0 = (const float*)d_in[4];
  const float* ww1 = (const float*)d_in[5];
  const float* ww2 = (const float*)d_in[6];
  const float* cw0 = (const float*)d_in[7];

  uint4* wsf = (uint4*)((char*)d_ws + 32768);
  unsigned short* green = (unsigned short*)((char*)d_ws + 67584);
  float* out = (float*)d_out;

  wt_kernel<<<8, 256, 0, stream>>>(fw0, fw1, fw2, ww0, ww1, ww2, wsf);
  green_kernel<<<16 * 8 * 64, 256, 0, stream>>>(mosaic, wsf, green);
  assemble_kernel<<<(16 * HH * WW) / 256, 256, 0, stream>>>(mosaic, green, cw0, out);
}

// Round 5
// 290.187 us; speedup vs baseline: 4.7416x; 1.0059x over previous
//
#include <hip/hip_runtime.h>
#include <cstdint>

#define HH 512
#define WW 512
#define TX 60          // output tile width; 9 tiles cover 512 (last partial)
// grid = 16 * 64 * 9 = 9216 blocks

typedef __attribute__((ext_vector_type(8)))  short    short8;
typedef __attribute__((ext_vector_type(16))) float    f32x16;
typedef __attribute__((ext_vector_type(2)))  unsigned u32x2;

union FragU { uint4 u; short8 s; };
union B8U   { u32x2 u2[2]; short8 s; };

// ---- LDS layout (bytes) ----
#define L1F_O  0        // 12 rows x 64 px x 24B
#define L1W_O  18432
#define L1RST  1536
#define MOS_O  36864    // 14 rows x 66 px x 8B (dead after L1 pass)
#define MOSR   528
#define L2F_O  36864    // aliases mosaic; 10 x 62 x 24B
#define L2W_O  51744
#define L2RST  1488
#define RELAY_O 0       // aliases dead L1F during L3 phase; 128 lanes x 32B
#define SMEMB  66624

__device__ __forceinline__ unsigned cvtpk(float a, float b) {
  unsigned r;
  asm("v_cvt_pk_bf16_f32 %0, %1, %2" : "=v"(r) : "v"(a), "v"(b));
  return r;
}
__device__ __forceinline__ unsigned rp(float a, float b, bool im) {
  unsigned r = cvtpk(fmaxf(a, 0.f), fmaxf(b, 0.f));
  return im ? r : 0u;
}
__device__ __forceinline__ unsigned rp2(float a, float b) {
  return cvtpk(fmaxf(a, 0.f), fmaxf(b, 0.f));
}
__device__ __forceinline__ unsigned short f2bf(float f) {
  union { float f; unsigned u; } v; v.f = f;
  unsigned r = v.u + 0x7fffu + ((v.u >> 16) & 1u);
  return (unsigned short)(r >> 16);
}
__device__ __forceinline__ float bf2f(unsigned short b) {
  union { unsigned u; float f; } v; v.u = ((unsigned)b) << 16;
  return v.f;
}
__device__ __forceinline__ float lo16(unsigned u) {
  union { unsigned v; float f; } x; x.v = u << 16; return x.f;
}
__device__ __forceinline__ float hi16(unsigned u) {
  union { unsigned v; float f; } x; x.v = u & 0xffff0000u; return x.f;
}

// ---------------- weight fragment packer (UNCHANGED mapping from round 4) ----------------
// 31 frags x 64 lanes x 16B.
// f 0-2: L1 merged (ky=f), rows: 0-11 = F co (fw0), 12-23 = W co (ww0);
//        slot sq = 2h + e/4 -> kx = sq (sq==3 zero).
// f 3-9: L2 F j / 10-16: L2 W j / 17-23: L3 F j / 24-30: L3 W j.
// Quad assignment (27 quads, off(q)=(q/9)*RST+8*(q%9)):
//   t=e/4==0: vertical domino  q = 9*h + j       (h-delta RST)
//   t==1:     horizontal domino q = H0[j] + h    (h-delta 8)
//   H0 = {7,16,18,20,22,24,25}; slot (j=6,t=1,h=0) dups quad 25 -> zero weights.
__global__ void wt_kernel(const float* __restrict__ fw0, const float* __restrict__ fw1,
                          const float* __restrict__ fw2, const float* __restrict__ ww0,
                          const float* __restrict__ ww1, const float* __restrict__ ww2,
                          uint4* __restrict__ wsf) {
  int t = blockIdx.x * 256 + threadIdx.x;
  if (t >= 31 * 64) return;
  int f = t >> 6, lane = t & 63;
  int h = (lane >> 5) & 1, m = lane & 31;
  unsigned short v[8];
#pragma unroll
  for (int e = 0; e < 8; ++e) {
    int half = e >> 2;
    int c4 = e & 3;
    float w = 0.f;
    if (f < 3) {
      int sq = 2 * h + half;
      if (sq < 3 && m < 24) {
        int kx = sq;
        w = (m < 12) ? fw0[(m * 4 + c4) * 9 + f * 3 + kx]
                     : ww0[((m - 12) * 4 + c4) * 9 + f * 3 + kx];
      }
    } else {
      int fi = f - 3, layer = fi / 14, path = (fi % 14) / 7, j = fi % 7;
      int q; bool real = (m < 12);
      if (half == 0) {
        q = 9 * h + j;
      } else {
        const int H0[7] = {7, 16, 18, 20, 22, 24, 25};
        q = H0[j] + h;
        if (j == 6 && h == 0) real = false;
      }
      if (real) {
        int tap = q / 3, ci = (q % 3) * 4 + c4;
        const float* src = layer ? (path ? ww2 : fw2) : (path ? ww1 : fw1);
        w = src[(m * 12 + ci) * 9 + tap];
      }
    }
    v[e] = f2bf(w);
  }
  uint4 o;
  o.x = (unsigned)v[0] | ((unsigned)v[1] << 16);
  o.y = (unsigned)v[2] | ((unsigned)v[3] << 16);
  o.z = (unsigned)v[4] | ((unsigned)v[5] << 16);
  o.w = (unsigned)v[6] | ((unsigned)v[7] << 16);
  wsf[t] = o;
}

// dual 12->12 conv group: 7 MFMAs each on F and W chains; all offsets immediates.
template<int RSTIN, int WIN>
__device__ __forceinline__ void conv12(const FragU* aF, const FragU* aW,
                                       const char* P0, const char* P1, int imm,
                                       f32x16& cF, f32x16& cW) {
  const int HI[7] = {56, RSTIN + 56, 2 * RSTIN, 2 * RSTIN + 16,
                     2 * RSTIN + 32, 2 * RSTIN + 48, 2 * RSTIN + 56};
#pragma unroll
  for (int j = 0; j < 7; ++j) {
    B8U bF, bW;
    bF.u2[0] = *(const u32x2*)(P0 + imm + 8 * j);
    bF.u2[1] = *(const u32x2*)(P1 + imm + HI[j]);
    bW.u2[0] = *(const u32x2*)(P0 + imm + 8 * j + WIN);
    bW.u2[1] = *(const u32x2*)(P1 + imm + HI[j] + WIN);
    cF = __builtin_amdgcn_mfma_f32_32x32x16_bf16(aF[j].s, bF.s, cF, 0, 0, 0);
    cW = __builtin_amdgcn_mfma_f32_32x32x16_bf16(aW[j].s, bW.s, cW, 0, 0, 0);
  }
}

// store M=12 C/D (h0 regs0-3->ci0-3, regs4-7->ci8-11; h1 regs0-3->ci4-7)
template<int WOUT>
__device__ __forceinline__ void store12(char* pO, int imm, const f32x16& cF,
                                        const f32x16& cW, bool im, int h) {
  u32x2 o;
  o.x = rp(cF[0], cF[1], im); o.y = rp(cF[2], cF[3], im);
  *(u32x2*)(pO + imm) = o;
  o.x = rp(cW[0], cW[1], im); o.y = rp(cW[2], cW[3], im);
  *(u32x2*)(pO + imm + WOUT) = o;
  if (h == 0) {
    o.x = rp(cF[4], cF[5], im); o.y = rp(cF[6], cF[7], im);
    *(u32x2*)(pO + imm + 16) = o;
    o.x = rp(cW[4], cW[5], im); o.y = rp(cW[6], cW[7], im);
    *(u32x2*)(pO + imm + WOUT + 16) = o;
  }
}

// ---------------- fused 3-layer x 2-path conv via MFMA + in-reg softmax green ----------------
__global__ __launch_bounds__(256, 2)
void green_kernel(const float* __restrict__ mosaic, const uint4* __restrict__ wsf,
                  unsigned short* __restrict__ green) {
  __shared__ __align__(16) char s[SMEMB];
  const int tid = threadIdx.x;
  const int lane = tid & 63;
  const int wv = __builtin_amdgcn_readfirstlane(tid >> 6);
  const int h = (lane >> 5) & 1, ln = lane & 31;
  const int ln8 = ln * 8, ln24 = ln * 24;
  const int bid = blockIdx.x;
  const int bx = bid % 9;
  const int t9 = bid / 9;
  const int by = t9 & 63, b = t9 >> 6;
  const int X0 = bx * TX, Y0 = by * 8;

  // ---- stage 0: mosaic tile 14x66, 4ch bf16-packed (8B/px), zero outside image ----
  {
    const float* mb = mosaic + (size_t)b * 4 * HH * WW;
    for (int p = tid; p < 14 * 66; p += 256) {
      int row = p / 66, col = p - row * 66;
      int gy = Y0 + row - 3, gx = X0 + col - 3;
      float c0 = 0.f, c1 = 0.f, c2 = 0.f, c3 = 0.f;
      if ((unsigned)gy < HH && (unsigned)gx < WW) {
        const float* mp = mb + (size_t)gy * WW + gx;
        c0 = mp[0]; c1 = mp[HH * WW]; c2 = mp[2 * HH * WW]; c3 = mp[3 * HH * WW];
      }
      u32x2 w = { cvtpk(c0, c1), cvtpk(c2, c3) };
      *(u32x2*)(s + MOS_O + row * MOSR + col * 8) = w;
    }
  }
  __syncthreads();

  // ---- L1: 4->12 both paths in one MFMA (M: F 0-11, W 12-23), out 12x64 ----
  {
    FragU a3[3];
#pragma unroll
    for (int q = 0; q < 3; ++q) a3[q].u = wsf[q * 64 + lane];
    const char* pLo = s + MOS_O + 3 * wv * MOSR + ln8 + 16 * h;  // sem kx = 2h
    const char* pHi = s + MOS_O + 3 * wv * MOSR + ln8 + 8;       // sem kx=1 (h0); pad (h1)
    char* pA = s + 3 * wv * L1RST + ln24 + (h ? L1F_O + 8  : L1F_O + 0);
    char* pB = s + 3 * wv * L1RST + ln24 + (h ? L1W_O + 0  : L1F_O + 16);
    char* pC = s + 3 * wv * L1RST + ln24 + (h ? L1W_O + 16 : L1W_O + 8);
    bool ck[2];
    ck[0] = (unsigned)(X0 + 0  + ln - 2) < WW;
    ck[1] = (unsigned)(X0 + 32 + ln - 2) < WW;
#pragma unroll
    for (int r = 0; r < 3; ++r) {
      const int ly = 3 * wv + r;
      const bool rowok = (unsigned)(Y0 + ly - 2) < HH;
#pragma unroll
      for (int g = 0; g < 2; ++g) {
        const int cb = g * 32;
        f32x16 c = {};
#pragma unroll
        for (int ky = 0; ky < 3; ++ky) {
          B8U bu;
          bu.u2[0] = *(const u32x2*)(pLo + (r + ky) * MOSR + cb * 8);
          bu.u2[1] = *(const u32x2*)(pHi + (r + ky) * MOSR + cb * 8);
          c = __builtin_amdgcn_mfma_f32_32x32x16_bf16(a3[ky].s, bu.s, c, 0, 0, 0);
        }
        const bool im = rowok && ck[g];
        u32x2 o;
        o.x = rp(c[0], c[1], im);   o.y = rp(c[2], c[3], im);
        *(u32x2*)(pA + r * L1RST + cb * 24) = o;   // h0: F ci0-3 | h1: F ci4-7
        o.x = rp(c[4], c[5], im);   o.y = rp(c[6], c[7], im);
        *(u32x2*)(pB + r * L1RST + cb * 24) = o;   // h0: F ci8-11 | h1: W ci0-3
        o.x = rp(c[8], c[9], im);   o.y = rp(c[10], c[11], im);
        *(u32x2*)(pC + r * L1RST + cb * 24) = o;   // h0: W ci4-7 | h1: W ci8-11
      }
    }
  }
  __syncthreads();

  // ---- L2: 12->12 both chains, out 10x62 ----
  {
    FragU aF[7], aW[7];
#pragma unroll
    for (int j = 0; j < 7; ++j) {
      aF[j].u = wsf[(3 + j) * 64 + lane];
      aW[j].u = wsf[(10 + j) * 64 + lane];
    }
    const char* P0 = s + L1F_O + (wv + h) * L1RST + ln24;
    const char* P1 = s + L1F_O + wv * L1RST + ln24 + 8 * h;
    char* bO0 = s + L2F_O + wv * L2RST + ln24 + (h ? 8 : 0);
    bool ck[2];
    ck[0] = (unsigned)(X0 + 0  + ln - 1) < WW;
    ck[1] = (unsigned)(X0 + 30 + ln - 1) < WW;
#pragma unroll
    for (int i = 0; i < 3; ++i) {
      const int ly = wv + 4 * i;
      if (ly < 10) {
        const bool rowok = (unsigned)(Y0 + ly - 1) < HH;
#pragma unroll
        for (int g = 0; g < 2; ++g) {
          const int cb = g * 30;
          f32x16 cF = {}, cW = {};
          conv12<L1RST, 18432>(aF, aW, P0, P1, i * 4 * L1RST + cb * 24, cF, cW);
          store12<14880>(bO0, i * 4 * L2RST + cb * 24, cF, cW, rowok && ck[g], h);
        }
      }
    }
  }
  __syncthreads();

  // ---- L3: 12->12 both chains, in-register + relay softmax, out 8x60 ----
  {
    FragU aF[7], aW[7];
#pragma unroll
    for (int j = 0; j < 7; ++j) {
      aF[j].u = wsf[(17 + j) * 64 + lane];
      aW[j].u = wsf[(24 + j) * 64 + lane];
    }
    const char* P0 = s + L2F_O + (2 * wv + h) * L2RST + ln24;
    const char* P1 = s + L2F_O + 2 * wv * L2RST + ln24 + 8 * h;
    char* slot = s + RELAY_O + (wv * 32 + ln) * 32;
#pragma unroll
    for (int r = 0; r < 2; ++r) {
#pragma unroll
      for (int g = 0; g < 2; ++g) {
        const int cb = g * 28;
        f32x16 cF = {}, cW = {};
        conv12<L2RST, 14880>(aF, aW, P0, P1, r * L2RST + cb * 24, cF, cW);
        const int cidx = (r * 2 + g) & 1;   // which half computes this call
        if (cidx == 0) {
          if (h) {            // h1 sends its ci4-7 (F then W)
            uint4 pay;
            pay.x = rp2(cF[0], cF[1]); pay.y = rp2(cF[2], cF[3]);
            pay.z = rp2(cW[0], cW[1]); pay.w = rp2(cW[2], cW[3]);
            *(uint4*)slot = pay;
          }
        } else {
          if (!h) {           // h0 sends ci0-3 + ci8-11 (F then W)
            uint4 pa, pb;
            pa.x = rp2(cF[0], cF[1]); pa.y = rp2(cF[2], cF[3]);
            pa.z = rp2(cF[4], cF[5]); pa.w = rp2(cF[6], cF[7]);
            pb.x = rp2(cW[0], cW[1]); pb.y = rp2(cW[2], cW[3]);
            pb.z = rp2(cW[4], cW[5]); pb.w = rp2(cW[6], cW[7]);
            *(uint4*)slot = pa;
            *(uint4*)(slot + 16) = pb;
          }
        }
        asm volatile("s_waitcnt lgkmcnt(0)" ::: "memory");
        if (h == cidx) {
          float F[12], Wv[12];
          if (cidx == 0) {    // h0 computes: own ci0-3 & ci8-11; relayed ci4-7
            const uint4 pay = *(const uint4*)slot;
#pragma unroll
            for (int c2 = 0; c2 < 4; ++c2) {
              F[c2]      = fmaxf(cF[c2], 0.f);
              F[8 + c2]  = fmaxf(cF[4 + c2], 0.f);
              Wv[c2]     = fmaxf(cW[c2], 0.f);
              Wv[8 + c2] = fmaxf(cW[4 + c2], 0.f);
            }
            F[4] = lo16(pay.x);  F[5] = hi16(pay.x);
            F[6] = lo16(pay.y);  F[7] = hi16(pay.y);
            Wv[4] = lo16(pay.z); Wv[5] = hi16(pay.z);
            Wv[6] = lo16(pay.w); Wv[7] = hi16(pay.w);
          } else {            // h1 computes: own ci4-7; relayed ci0-3 & ci8-11
            const uint4 pa = *(const uint4*)slot;
            const uint4 pb = *(const uint4*)(slot + 16);
#pragma unroll
            for (int c2 = 0; c2 < 4; ++c2) {
              F[4 + c2]  = fmaxf(cF[c2], 0.f);
              Wv[4 + c2] = fmaxf(cW[c2], 0.f);
            }
            F[0] = lo16(pa.x);   F[1] = hi16(pa.x);
            F[2] = lo16(pa.y);   F[3] = hi16(pa.y);
            F[8] = lo16(pa.z);   F[9] = hi16(pa.z);
            F[10] = lo16(pa.w);  F[11] = hi16(pa.w);
            Wv[0] = lo16(pb.x);  Wv[1] = hi16(pb.x);
            Wv[2] = lo16(pb.y);  Wv[3] = hi16(pb.y);
            Wv[8] = lo16(pb.z);  Wv[9] = hi16(pb.z);
            Wv[10] = lo16(pb.w); Wv[11] = hi16(pb.w);
          }
          float m = 0.f;
#pragma unroll
          for (int c2 = 0; c2 < 12; ++c2) m = fmaxf(m, Wv[c2]);
          float sum = 0.f, s0 = 0.f, s1 = 0.f;
#pragma unroll
          for (int c2 = 0; c2 < 12; ++c2) {
            const float e = __expf(Wv[c2] - m);
            sum += e;
            if (c2 < 6) s0 = fmaf(F[c2], e, s0);
            else        s1 = fmaf(F[c2], e, s1);
          }
          const float inv = 1.f / sum;
          const unsigned pg = cvtpk(s0 * inv, s1 * inv);
          const int gy = Y0 + 2 * wv + r;
          const int gx = X0 + cb + ln;
          if ((unsigned)gx < WW) {
            green[((b * 2 + 0) * HH + gy) * WW + gx] = (unsigned short)pg;
            green[((b * 2 + 1) * HH + gy) * WW + gx] = (unsigned short)(pg >> 16);
          }
        }
      }
    }
  }
}

// ---------------- chroma conv 2->6 + pixel-shuffle assembly ----------------
__global__ __launch_bounds__(256)
void assemble_kernel(const float* __restrict__ mosaic, const unsigned short* __restrict__ green,
                     const float* __restrict__ cw0, float* __restrict__ out) {
  const int t = blockIdx.x * 256 + threadIdx.x;
  const int x = t & (WW - 1);
  const int y = (t >> 9) & (HH - 1);
  const int b = t >> 18;

  const int p = y * WW + x;
  const float* __restrict__ mb = mosaic + (size_t)b * 4 * HH * WW;
  const unsigned short* __restrict__ gb = green + (size_t)b * 2 * HH * WW;

  const float m0 = mb[p];
  const float m1 = mb[HH * WW + p];
  const float m2 = mb[2 * HH * WW + p];
  const float m3 = mb[3 * HH * WW + p];
  const float g0 = bf2f(gb[p]);
  const float g1 = bf2f(gb[HH * WW + p]);

  float cd[6] = {0.f, 0.f, 0.f, 0.f, 0.f, 0.f};
#pragma unroll
  for (int ky = 0; ky < 3; ++ky) {
#pragma unroll
    for (int kx = 0; kx < 3; ++kx) {
      const int yy = y + ky - 1, xx = x + kx - 1;
      float c0 = 0.f, c1 = 0.f;
      if ((unsigned)yy < HH && (unsigned)xx < WW) {
        const int q = yy * WW + xx;
        c0 = mb[HH * WW + q]     - bf2f(gb[q]);
        c1 = mb[2 * HH * WW + q] - bf2f(gb[HH * WW + q]);
      }
      const int k = ky * 3 + kx;
#pragma unroll
      for (int o = 0; o < 6; ++o) {
        cd[o] = fmaf(c0, cw0[(o * 2 + 0) * 9 + k], cd[o]);
        cd[o] = fmaf(c1, cw0[(o * 2 + 1) * 9 + k], cd[o]);
      }
    }
  }
  const float cp0 = cd[0] + m0;
  const float cp1 = cd[1] + g1;
  const float cp2 = cd[2] + m3;
  const float cp3 = cd[3] + m0;
  const float cp4 = cd[4] + g0;
  const float cp5 = cd[5] + m3;

  const int W2 = 2 * WW;
  const size_t plane = (size_t)(2 * HH) * W2;
  size_t base = ((size_t)(b * 3) * (2 * HH) + 2 * y) * W2 + 2 * x;
  *(float2*)(out + base)              = make_float2(cp0, m1);
  *(float2*)(out + base + W2)         = make_float2(cp1, cp2);
  *(float2*)(out + base + plane)      = make_float2(m0, g0);
  *(float2*)(out + base + plane + W2) = make_float2(g1, m3);
  *(float2*)(out + base + 2 * plane)      = make_float2(cp3, cp4);
  *(float2*)(out + base + 2 * plane + W2) = make_float2(m2, cp5);
}

extern "C" void kernel_launch(void* const* d_in, const int* in_sizes, int n_in,
                              void* d_out, int out_size, void* d_ws, size_t ws_size,
                              hipStream_t stream) {
  const float* mosaic = (const float*)d_in[0];
  const float* fw0 = (const float*)d_in[1];
  const float* fw1 = (const float*)d_in[2];
  const float* fw2 = (const float*)d_in[3];
  const float* ww0 = (const float*)d_in[4];
  const float* ww1 = (const float*)d_in[5];
  const float* ww2 = (const float*)d_in[6];
  const float* cw0 = (const float*)d_in[7];

  uint4* wsf = (uint4*)((char*)d_ws + 32768);
  unsigned short* green = (unsigned short*)((char*)d_ws + 67584);
  float* out = (float*)d_out;

  wt_kernel<<<8, 256, 0, stream>>>(fw0, fw1, fw2, ww0, ww1, ww2, wsf);
  green_kernel<<<16 * 64 * 9, 256, 0, stream>>>(mosaic, wsf, green);
  assemble_kernel<<<(16 * HH * WW) / 256, 256, 0, stream>>>(mosaic, green, cw0, out);
}

// Round 6
// 216.683 us; speedup vs baseline: 6.3500x; 1.3392x over previous
//
#include <hip/hip_runtime.h>
#include <cstdint>

#define HH 512
#define WW 512
#define TX 60          // output tile width; 9 tiles cover 512 (last partial)
// grid = 16 * 64 * 9 = 9216 blocks

typedef __attribute__((ext_vector_type(8)))  short    short8;
typedef __attribute__((ext_vector_type(16))) float    f32x16;
typedef __attribute__((ext_vector_type(2)))  unsigned u32x2;
typedef long long lng;

union FragU { uint4 u; short8 s; };
union U4L   { uint4 u; lng l[2]; };
union B8U   { u32x2 u2[2]; short8 s; };
union BL    { unsigned w[2]; lng l; };

// ---- LDS layout (bytes) ----
// fp8 act slot = 12B (ci0-3 @0, ci4-7 @4, ci8-11 @8)
#define L1F_O  0        // 12 rows x 64 px x 12B
#define L1W_O  9216
#define L1RST  768
#define MOS_O  18432    // 14 rows x 66 px x 8B bf16 (dead after L1 pass)
#define MOSR   528
#define L2F_O  18432    // aliases mosaic; 10 x 62 x 12B
#define L2W_O  25872
#define L2RST  744
#define RELAY_O 0       // aliases dead L1F during L3 phase; 128 slots x 48B
#define SMEMB  33312

__device__ __forceinline__ unsigned cvtpk(float a, float b) {
  unsigned r;
  asm("v_cvt_pk_bf16_f32 %0, %1, %2" : "=v"(r) : "v"(a), "v"(b));
  return r;
}
__device__ __forceinline__ unsigned rpk8(float a, float b, float c, float d, bool im) {
  int r = __builtin_amdgcn_cvt_pk_fp8_f32(fmaxf(a, 0.f), fmaxf(b, 0.f), 0, false);
  r = __builtin_amdgcn_cvt_pk_fp8_f32(fmaxf(c, 0.f), fmaxf(d, 0.f), r, true);
  return im ? (unsigned)r : 0u;
}
__device__ __forceinline__ unsigned short f2bf(float f) {
  union { float f; unsigned u; } v; v.f = f;
  unsigned r = v.u + 0x7fffu + ((v.u >> 16) & 1u);
  return (unsigned short)(r >> 16);
}
__device__ __forceinline__ float bf2f(unsigned short b) {
  union { unsigned u; float f; } v; v.u = ((unsigned)b) << 16;
  return v.f;
}
__device__ __forceinline__ float lo16(unsigned u) {
  union { unsigned v; float f; } x; x.v = u << 16; return x.f;
}
__device__ __forceinline__ float hi16(unsigned u) {
  union { unsigned v; float f; } x; x.v = u & 0xffff0000u; return x.f;
}
__device__ __forceinline__ lng rd8(const char* p) {
  BL t;
  t.w[0] = *(const unsigned*)p;
  t.w[1] = *(const unsigned*)(p + 4);
  return t.l;
}

// ---------------- weight fragment packer ----------------
// f 0-2: L1 merged bf16 (ky=f), rows 0-11 = fw0 co, 12-23 = ww0 co;
//        slot sq = 2h + e/4 -> kx = sq (sq==3 zero). 16B/lane.
// f 3-9: L2 F j / 10-16: L2 W j / 17-23: L3 F j / 24-30: L3 W j — fp8, 8B/lane.
// fp8 quads (27, quad q covers kappa 4q..4q+3; kappa = tap*12+ci;
// off(q) = (q/9)*RST + 4*(q%9)). (j,h) -> byte-adjacent quad pair:
//   j0:(0,1)/(2,3) j1:(4,5)/(6,7) j2:(9,10)/(11,12) j3:(13,14)/(15,16)
//   j4:(18,19)/(20,21) j5:(22,23)/(24,25) j6:(8,17)split / (26,pad)
__global__ void wt_kernel(const float* __restrict__ fw0, const float* __restrict__ fw1,
                          const float* __restrict__ fw2, const float* __restrict__ ww0,
                          const float* __restrict__ ww1, const float* __restrict__ ww2,
                          uint4* __restrict__ wsf) {
  int t = blockIdx.x * 256 + threadIdx.x;
  if (t >= 31 * 64) return;
  int f = t >> 6, lane = t & 63;
  int h = (lane >> 5) & 1, m = lane & 31;
  uint4 o = make_uint4(0, 0, 0, 0);
  if (f < 3) {
    unsigned short v[8];
#pragma unroll
    for (int e = 0; e < 8; ++e) {
      int sq = 2 * h + (e >> 2);
      int c4 = e & 3;
      float w = 0.f;
      if (sq < 3 && m < 24) {
        w = (m < 12) ? fw0[(m * 4 + c4) * 9 + f * 3 + sq]
                     : ww0[((m - 12) * 4 + c4) * 9 + f * 3 + sq];
      }
      v[e] = f2bf(w);
    }
    o.x = (unsigned)v[0] | ((unsigned)v[1] << 16);
    o.y = (unsigned)v[2] | ((unsigned)v[3] << 16);
    o.z = (unsigned)v[4] | ((unsigned)v[5] << 16);
    o.w = (unsigned)v[6] | ((unsigned)v[7] << 16);
  } else {
    const int PR[7][2][2] = {
      {{0, 1}, {2, 3}}, {{4, 5}, {6, 7}}, {{9, 10}, {11, 12}},
      {{13, 14}, {15, 16}}, {{18, 19}, {20, 21}}, {{22, 23}, {24, 25}},
      {{8, 17}, {26, -1}}};
    int fi = f - 3, layer = fi / 14, path = (fi % 14) / 7, j = fi % 7;
    const float* src = layer ? (path ? ww2 : fw2) : (path ? ww1 : fw1);
    float wv[8];
#pragma unroll
    for (int p = 0; p < 8; ++p) {
      int q = PR[j][h][p >> 2];
      int c = p & 3;
      float w = 0.f;
      if (q >= 0 && m < 12) {
        int kap = 4 * q + c;
        int tap = kap / 12, ci = kap % 12;
        w = src[(m * 12 + ci) * 9 + tap];
      }
      wv[p] = w;
    }
    int x = __builtin_amdgcn_cvt_pk_fp8_f32(wv[0], wv[1], 0, false);
    x = __builtin_amdgcn_cvt_pk_fp8_f32(wv[2], wv[3], x, true);
    int y = __builtin_amdgcn_cvt_pk_fp8_f32(wv[4], wv[5], 0, false);
    y = __builtin_amdgcn_cvt_pk_fp8_f32(wv[6], wv[7], y, true);
    o.x = (unsigned)x; o.y = (unsigned)y;
  }
  wsf[t] = o;
}

// dual fp8 12->12 conv group: 7 MFMAs each on F and W chains.
// Ph = base + 8h; Pa = base + (h?2RST:0); Pb = base + (h?2RST:RST).
template<int RST, int WIN>
__device__ __forceinline__ void conv12f8(const lng* aF, const lng* aW,
                                         const char* Ph, const char* Pa, const char* Pb,
                                         int imm, f32x16& cF, f32x16& cW) {
  const int IM[6] = {0, 16, RST, RST + 16, 2 * RST, 2 * RST + 16};
#pragma unroll
  for (int j = 0; j < 6; ++j) {
    lng bF = rd8(Ph + imm + IM[j]);
    lng bW = rd8(Ph + imm + IM[j] + WIN);
    cF = __builtin_amdgcn_mfma_f32_32x32x16_fp8_fp8(aF[j], bF, cF, 0, 0, 0);
    cW = __builtin_amdgcn_mfma_f32_32x32x16_fp8_fp8(aW[j], bW, cW, 0, 0, 0);
  }
  {
    BL bF, bW;
    bF.w[0] = *(const unsigned*)(Pa + imm + 32);
    bF.w[1] = *(const unsigned*)(Pb + imm + 32);
    bW.w[0] = *(const unsigned*)(Pa + imm + 32 + WIN);
    bW.w[1] = *(const unsigned*)(Pb + imm + 32 + WIN);
    cF = __builtin_amdgcn_mfma_f32_32x32x16_fp8_fp8(aF[6], bF.l, cF, 0, 0, 0);
    cW = __builtin_amdgcn_mfma_f32_32x32x16_fp8_fp8(aW[6], bW.l, cW, 0, 0, 0);
  }
}

// store M=12 C/D as fp8 (h0 regs0-3->ci0-3 @+0, regs4-7->ci8-11 @+8; h1 regs0-3->ci4-7 @+4)
// pO already includes +4h.
template<int WOUT>
__device__ __forceinline__ void store12f8(char* pO, int imm, const f32x16& cF,
                                          const f32x16& cW, bool im, int h) {
  *(unsigned*)(pO + imm) = rpk8(cF[0], cF[1], cF[2], cF[3], im);
  *(unsigned*)(pO + imm + WOUT) = rpk8(cW[0], cW[1], cW[2], cW[3], im);
  if (h == 0) {
    *(unsigned*)(pO + imm + 8) = rpk8(cF[4], cF[5], cF[6], cF[7], im);
    *(unsigned*)(pO + imm + WOUT + 8) = rpk8(cW[4], cW[5], cW[6], cW[7], im);
  }
}

// ---------------- fused 3-layer x 2-path conv via MFMA + in-reg softmax green ----------------
__global__ __launch_bounds__(256, 4)
void green_kernel(const float* __restrict__ mosaic, const uint4* __restrict__ wsf,
                  unsigned short* __restrict__ green) {
  __shared__ __align__(16) char s[SMEMB];
  const int tid = threadIdx.x;
  const int lane = tid & 63;
  const int wv = __builtin_amdgcn_readfirstlane(tid >> 6);
  const int h = (lane >> 5) & 1, ln = lane & 31;
  const int ln8 = ln * 8, ln12 = ln * 12;
  const int bid = blockIdx.x;
  const int bx = bid % 9;
  const int t9 = bid / 9;
  const int by = t9 & 63, b = t9 >> 6;
  const int X0 = bx * TX, Y0 = by * 8;

  // ---- stage 0: mosaic tile 14x66, 4ch bf16-packed (8B/px), zero outside image ----
  {
    const float* mb = mosaic + (size_t)b * 4 * HH * WW;
    for (int p = tid; p < 14 * 66; p += 256) {
      int row = p / 66, col = p - row * 66;
      int gy = Y0 + row - 3, gx = X0 + col - 3;
      float c0 = 0.f, c1 = 0.f, c2 = 0.f, c3 = 0.f;
      if ((unsigned)gy < HH && (unsigned)gx < WW) {
        const float* mp = mb + (size_t)gy * WW + gx;
        c0 = mp[0]; c1 = mp[HH * WW]; c2 = mp[2 * HH * WW]; c3 = mp[3 * HH * WW];
      }
      u32x2 w = { cvtpk(c0, c1), cvtpk(c2, c3) };
      *(u32x2*)(s + MOS_O + row * MOSR + col * 8) = w;
    }
  }
  __syncthreads();

  // ---- L1: 4->12 both paths in one bf16 MFMA (M: F 0-11, W 12-23), out 12x64 fp8 ----
  {
    FragU a3[3];
#pragma unroll
    for (int q = 0; q < 3; ++q) a3[q].u = wsf[q * 64 + lane];
    const char* pLo = s + MOS_O + 3 * wv * MOSR + ln8 + 16 * h;  // sem kx = 2h
    const char* pHi = s + MOS_O + 3 * wv * MOSR + ln8 + 8;       // sem kx=1 (h0); pad (h1)
    char* base = s + 3 * wv * L1RST + ln12;
    char* pA = base + L1F_O + 4 * h;                 // F d0 (h0) / F d1 (h1)
    char* pB = h ? base + L1W_O : base + L1F_O + 8;  // W d0 (h1) / F d2 (h0)
    char* pC = base + L1W_O + (h ? 8 : 4);           // W d2 (h1) / W d1 (h0)
    bool ck[2];
    ck[0] = (unsigned)(X0 + 0  + ln - 2) < WW;
    ck[1] = (unsigned)(X0 + 32 + ln - 2) < WW;
#pragma unroll
    for (int r = 0; r < 3; ++r) {
      const int ly = 3 * wv + r;
      const bool rowok = (unsigned)(Y0 + ly - 2) < HH;
#pragma unroll
      for (int g = 0; g < 2; ++g) {
        const int cb = g * 32;
        f32x16 c = {};
#pragma unroll
        for (int ky = 0; ky < 3; ++ky) {
          B8U bu;
          bu.u2[0] = *(const u32x2*)(pLo + (r + ky) * MOSR + cb * 8);
          bu.u2[1] = *(const u32x2*)(pHi + (r + ky) * MOSR + cb * 8);
          c = __builtin_amdgcn_mfma_f32_32x32x16_bf16(a3[ky].s, bu.s, c, 0, 0, 0);
        }
        const bool im = rowok && ck[g];
        *(unsigned*)(pA + r * L1RST + cb * 12) = rpk8(c[0], c[1], c[2], c[3], im);
        *(unsigned*)(pB + r * L1RST + cb * 12) = rpk8(c[4], c[5], c[6], c[7], im);
        *(unsigned*)(pC + r * L1RST + cb * 12) = rpk8(c[8], c[9], c[10], c[11], im);
      }
    }
  }
  __syncthreads();

  // ---- L2: 12->12 both chains fp8, out 10x62 ----
  {
    lng aF[7], aW[7];
#pragma unroll
    for (int j = 0; j < 7; ++j) {
      U4L u; u.u = wsf[(3 + j) * 64 + lane];  aF[j] = u.l[0];
      U4L v; v.u = wsf[(10 + j) * 64 + lane]; aW[j] = v.l[0];
    }
    const char* base = s + L1F_O + wv * L1RST + ln12;
    const char* Ph = base + 8 * h;
    const char* Pa = base + (h ? 2 * L1RST : 0);
    const char* Pb = base + (h ? 2 * L1RST : L1RST);
    char* bO0 = s + L2F_O + wv * L2RST + ln12 + 4 * h;
    bool ck[2];
    ck[0] = (unsigned)(X0 + 0  + ln - 1) < WW;
    ck[1] = (unsigned)(X0 + 30 + ln - 1) < WW;
#pragma unroll
    for (int i = 0; i < 3; ++i) {
      const int ly = wv + 4 * i;
      if (ly < 10) {
        const bool rowok = (unsigned)(Y0 + ly - 1) < HH;
#pragma unroll
        for (int g = 0; g < 2; ++g) {
          const int cb = g * 30;
          f32x16 cF = {}, cW = {};
          conv12f8<L1RST, 9216>(aF, aW, Ph, Pa, Pb, i * 4 * L1RST + cb * 12, cF, cW);
          store12f8<7440>(bO0, i * 4 * L2RST + cb * 12, cF, cW, rowok && ck[g], h);
        }
      }
    }
  }
  __syncthreads();

  // ---- L3: 12->12 both chains fp8, in-register + relay softmax, out 8x60 ----
  {
    lng aF[7], aW[7];
#pragma unroll
    for (int j = 0; j < 7; ++j) {
      U4L u; u.u = wsf[(17 + j) * 64 + lane]; aF[j] = u.l[0];
      U4L v; v.u = wsf[(24 + j) * 64 + lane]; aW[j] = v.l[0];
    }
    const char* base = s + L2F_O + 2 * wv * L2RST + ln12;
    const char* Ph = base + 8 * h;
    const char* Pa = base + (h ? 2 * L2RST : 0);
    const char* Pb = base + (h ? 2 * L2RST : L2RST);
    char* slot = s + RELAY_O + (wv * 32 + ln) * 48;
#pragma unroll
    for (int r = 0; r < 2; ++r) {
#pragma unroll
      for (int g = 0; g < 2; ++g) {
        const int cb = g * 28;
        f32x16 cF = {}, cW = {};
        conv12f8<L2RST, 7440>(aF, aW, Ph, Pa, Pb, r * L2RST + cb * 12, cF, cW);
        const int cidx = (r * 2 + g) & 1;   // which half computes this call
        if (cidx == 0) {
          if (h) {            // h1 sends its ci4-7 (F then W) as bf16
            uint4 pay;
            pay.x = cvtpk(fmaxf(cF[0], 0.f), fmaxf(cF[1], 0.f));
            pay.y = cvtpk(fmaxf(cF[2], 0.f), fmaxf(cF[3], 0.f));
            pay.z = cvtpk(fmaxf(cW[0], 0.f), fmaxf(cW[1], 0.f));
            pay.w = cvtpk(fmaxf(cW[2], 0.f), fmaxf(cW[3], 0.f));
            *(uint4*)slot = pay;
          }
        } else {
          if (!h) {           // h0 sends ci0-3 + ci8-11 (F then W)
            uint4 pa, pb;
            pa.x = cvtpk(fmaxf(cF[0], 0.f), fmaxf(cF[1], 0.f));
            pa.y = cvtpk(fmaxf(cF[2], 0.f), fmaxf(cF[3], 0.f));
            pa.z = cvtpk(fmaxf(cF[4], 0.f), fmaxf(cF[5], 0.f));
            pa.w = cvtpk(fmaxf(cF[6], 0.f), fmaxf(cF[7], 0.f));
            pb.x = cvtpk(fmaxf(cW[0], 0.f), fmaxf(cW[1], 0.f));
            pb.y = cvtpk(fmaxf(cW[2], 0.f), fmaxf(cW[3], 0.f));
            pb.z = cvtpk(fmaxf(cW[4], 0.f), fmaxf(cW[5], 0.f));
            pb.w = cvtpk(fmaxf(cW[6], 0.f), fmaxf(cW[7], 0.f));
            *(uint4*)slot = pa;
            *(uint4*)(slot + 16) = pb;
          }
        }
        asm volatile("s_waitcnt lgkmcnt(0)" ::: "memory");
        if (h == cidx) {
          float F[12], Wv[12];
          if (cidx == 0) {    // h0 computes: own ci0-3 & ci8-11; relayed ci4-7
            const uint4 pay = *(const uint4*)slot;
#pragma unroll
            for (int c2 = 0; c2 < 4; ++c2) {
              F[c2]      = fmaxf(cF[c2], 0.f);
              F[8 + c2]  = fmaxf(cF[4 + c2], 0.f);
              Wv[c2]     = fmaxf(cW[c2], 0.f);
              Wv[8 + c2] = fmaxf(cW[4 + c2], 0.f);
            }
            F[4] = lo16(pay.x);  F[5] = hi16(pay.x);
            F[6] = lo16(pay.y);  F[7] = hi16(pay.y);
            Wv[4] = lo16(pay.z); Wv[5] = hi16(pay.z);
            Wv[6] = lo16(pay.w); Wv[7] = hi16(pay.w);
          } else {            // h1 computes: own ci4-7; relayed ci0-3 & ci8-11
            const uint4 pa = *(const uint4*)slot;
            const uint4 pb = *(const uint4*)(slot + 16);
#pragma unroll
            for (int c2 = 0; c2 < 4; ++c2) {
              F[4 + c2]  = fmaxf(cF[c2], 0.f);
              Wv[4 + c2] = fmaxf(cW[c2], 0.f);
            }
            F[0] = lo16(pa.x);   F[1] = hi16(pa.x);
            F[2] = lo16(pa.y);   F[3] = hi16(pa.y);
            F[8] = lo16(pa.z);   F[9] = hi16(pa.z);
            F[10] = lo16(pa.w);  F[11] = hi16(pa.w);
            Wv[0] = lo16(pb.x);  Wv[1] = hi16(pb.x);
            Wv[2] = lo16(pb.y);  Wv[3] = hi16(pb.y);
            Wv[8] = lo16(pb.z);  Wv[9] = hi16(pb.z);
            Wv[10] = lo16(pb.w); Wv[11] = hi16(pb.w);
          }
          float m = 0.f;
#pragma unroll
          for (int c2 = 0; c2 < 12; ++c2) m = fmaxf(m, Wv[c2]);
          float sum = 0.f, s0 = 0.f, s1 = 0.f;
#pragma unroll
          for (int c2 = 0; c2 < 12; ++c2) {
            const float e = __expf(Wv[c2] - m);
            sum += e;
            if (c2 < 6) s0 = fmaf(F[c2], e, s0);
            else        s1 = fmaf(F[c2], e, s1);
          }
          const float inv = 1.f / sum;
          const unsigned pg = cvtpk(s0 * inv, s1 * inv);
          const int gy = Y0 + 2 * wv + r;
          const int gx = X0 + cb + ln;
          if ((unsigned)gx < WW) {
            green[((b * 2 + 0) * HH + gy) * WW + gx] = (unsigned short)pg;
            green[((b * 2 + 1) * HH + gy) * WW + gx] = (unsigned short)(pg >> 16);
          }
        }
      }
    }
  }
}

// ---------------- chroma conv 2->6 + pixel-shuffle assembly ----------------
__global__ __launch_bounds__(256)
void assemble_kernel(const float* __restrict__ mosaic, const unsigned short* __restrict__ green,
                     const float* __restrict__ cw0, float* __restrict__ out) {
  const int t = blockIdx.x * 256 + threadIdx.x;
  const int x = t & (WW - 1);
  const int y = (t >> 9) & (HH - 1);
  const int b = t >> 18;

  const int p = y * WW + x;
  const float* __restrict__ mb = mosaic + (size_t)b * 4 * HH * WW;
  const unsigned short* __restrict__ gb = green + (size_t)b * 2 * HH * WW;

  const float m0 = mb[p];
  const float m1 = mb[HH * WW + p];
  const float m2 = mb[2 * HH * WW + p];
  const float m3 = mb[3 * HH * WW + p];
  const float g0 = bf2f(gb[p]);
  const float g1 = bf2f(gb[HH * WW + p]);

  float cd[6] = {0.f, 0.f, 0.f, 0.f, 0.f, 0.f};
#pragma unroll
  for (int ky = 0; ky < 3; ++ky) {
#pragma unroll
    for (int kx = 0; kx < 3; ++kx) {
      const int yy = y + ky - 1, xx = x + kx - 1;
      float c0 = 0.f, c1 = 0.f;
      if ((unsigned)yy < HH && (unsigned)xx < WW) {
        const int q = yy * WW + xx;
        c0 = mb[HH * WW + q]     - bf2f(gb[q]);
        c1 = mb[2 * HH * WW + q] - bf2f(gb[HH * WW + q]);
      }
      const int k = ky * 3 + kx;
#pragma unroll
      for (int o = 0; o < 6; ++o) {
        cd[o] = fmaf(c0, cw0[(o * 2 + 0) * 9 + k], cd[o]);
        cd[o] = fmaf(c1, cw0[(o * 2 + 1) * 9 + k], cd[o]);
      }
    }
  }
  const float cp0 = cd[0] + m0;
  const float cp1 = cd[1] + g1;
  const float cp2 = cd[2] + m3;
  const float cp3 = cd[3] + m0;
  const float cp4 = cd[4] + g0;
  const float cp5 = cd[5] + m3;

  const int W2 = 2 * WW;
  const size_t plane = (size_t)(2 * HH) * W2;
  size_t base = ((size_t)(b * 3) * (2 * HH) + 2 * y) * W2 + 2 * x;
  *(float2*)(out + base)              = make_float2(cp0, m1);
  *(float2*)(out + base + W2)         = make_float2(cp1, cp2);
  *(float2*)(out + base + plane)      = make_float2(m0, g0);
  *(float2*)(out + base + plane + W2) = make_float2(g1, m3);
  *(float2*)(out + base + 2 * plane)      = make_float2(cp3, cp4);
  *(float2*)(out + base + 2 * plane + W2) = make_float2(m2, cp5);
}

extern "C" void kernel_launch(void* const* d_in, const int* in_sizes, int n_in,
                              void* d_out, int out_size, void* d_ws, size_t ws_size,
                              hipStream_t stream) {
  const float* mosaic = (const float*)d_in[0];
  const float* fw0 = (const float*)d_in[1];
  const float* fw1 = (const float*)d_in[2];
  const float* fw2 = (const float*)d_in[3];
  const float* ww0 = (const float*)d_in[4];
  const float* ww1 = (const float*)d_in[5];
  const float* ww2 = (const float*)d_in[6];
  const float* cw0 = (const float*)d_in[7];

  uint4* wsf = (uint4*)((char*)d_ws + 32768);
  unsigned short* green = (unsigned short*)((char*)d_ws + 67584);
  float* out = (float*)d_out;

  wt_kernel<<<8, 256, 0, stream>>>(fw0, fw1, fw2, ww0, ww1, ww2, wsf);
  green_kernel<<<16 * 64 * 9, 256, 0, stream>>>(mosaic, wsf, green);
  assemble_kernel<<<(16 * HH * WW) / 256, 256, 0, stream>>>(mosaic, green, cw0, out);
}